// Round 2
// baseline (598.898 us; speedup 1.0000x reference)
//
#include <hip/hip_runtime.h>
#include <hip/hip_bf16.h>
#include <stdint.h>

// Problem constants
#define N_NODES 8192
#define F_IN    768
#define F_OUT   128

typedef __bf16 bf16_t;
typedef __bf16 bf16x8 __attribute__((ext_vector_type(8)));
typedef float  f32x4  __attribute__((ext_vector_type(4)));
typedef unsigned short u16x4 __attribute__((ext_vector_type(4)));
typedef unsigned short u16x8 __attribute__((ext_vector_type(8)));

static __device__ __forceinline__ unsigned short bf16_bits(float x) {
  bf16_t b = (bf16_t)x;   // RTNE convert
  return __builtin_bit_cast(unsigned short, b);
}

// ---------------------------------------------------------------------------
// prep_wt: WT[col][k] = bf16(W[k][col])   (128 x 768 bf16, L2-resident)
// ---------------------------------------------------------------------------
__global__ __launch_bounds__(256) void prep_wt(const float* __restrict__ W,
                                               bf16_t* __restrict__ WT) {
  int gid = blockIdx.x * 256 + threadIdx.x;   // 24576 total
  int col = gid / 192;
  int kq  = gid % 192;
  int k0  = kq * 4;
  u16x4 u;
#pragma unroll
  for (int i = 0; i < 4; ++i)
    u[i] = bf16_bits(W[(k0 + i) * F_OUT + col]);
  *(u16x4*)(WT + col * F_IN + k0) = u;
}

// ---------------------------------------------------------------------------
// prep_waux: wxs[k] = sum_c W[k][c]*a[c];  wxd[k] = sum_c W[k][c]*a[128+c]
// ---------------------------------------------------------------------------
__global__ __launch_bounds__(256) void prep_waux(const float* __restrict__ W,
                                                 const float* __restrict__ a,
                                                 float* __restrict__ wxs,
                                                 float* __restrict__ wxd) {
  const int wave = threadIdx.x >> 6;
  const int lane = threadIdx.x & 63;
  const int row  = blockIdx.x * 4 + wave;     // 0..767
  float w0 = W[row * F_OUT + lane];
  float w1 = W[row * F_OUT + 64 + lane];
  float s = w0 * a[lane]       + w1 * a[64 + lane];
  float d = w0 * a[128 + lane] + w1 * a[192 + lane];
#pragma unroll
  for (int m = 1; m <= 32; m <<= 1) {
    s += __shfl_xor(s, m);
    d += __shfl_xor(d, m);
  }
  if (lane == 0) { wxs[row] = s; wxd[row] = d; }
}

// ---------------------------------------------------------------------------
// hp_kernel: Hp = H@W, stored transposed in split bf16 precision:
//   HpTh[col][row] = bf16(Hp), HpTl[col][row] = bf16(Hp - fp32(HpTh))
// src/dst = H @ wxs/wxd fused into the fp32 H loads (exact fp32).
// BM=32 rows/block, grid 256 x 256. bf16 MFMA 16x16x32.
// ---------------------------------------------------------------------------
__global__ __launch_bounds__(256, 2) void hp_kernel(
    const float* __restrict__ H, const bf16_t* __restrict__ WT,
    const float* __restrict__ wxs, const float* __restrict__ wxd,
    bf16_t* __restrict__ HpTh, bf16_t* __restrict__ HpTl,
    float* __restrict__ srcv, float* __restrict__ dstv)
{
  __shared__ unsigned short h_s[32 * 64];   // bf16 H tile, swizzled
  __shared__ float ws_s[F_IN];
  __shared__ float wd_s[F_IN];
  __shared__ unsigned int t_s[128 * 40];    // packed hi|lo transpose staging

  const int tid  = threadIdx.x;
  const int wave = tid >> 6;
  const int lane = tid & 63;
  const int l15  = lane & 15;
  const int g    = lane >> 4;
  const int row0 = blockIdx.x * 32;
  const int lrow = tid >> 4;   // 0..15
  const int q    = tid & 15;

  for (int i = tid; i < F_IN; i += 256) { ws_s[i] = wxs[i]; wd_s[i] = wxd[i]; }

  f32x4 zero4 = {0.f, 0.f, 0.f, 0.f};
  f32x4 acc[2][2];
#pragma unroll
  for (int i = 0; i < 2; ++i)
#pragma unroll
    for (int j = 0; j < 2; ++j) acc[i][j] = zero4;
  float ps0 = 0.f, ps1 = 0.f, pd0 = 0.f, pd1 = 0.f;

  __syncthreads();

  for (int c = 0; c < F_IN / 64; ++c) {
    const int k0 = c * 64;
    f32x4 h0 = *(const f32x4*)&H[(size_t)(row0 + lrow) * F_IN + k0 + q * 4];
    f32x4 h1 = *(const f32x4*)&H[(size_t)(row0 + 16 + lrow) * F_IN + k0 + q * 4];
    f32x4 as = *(const f32x4*)&ws_s[k0 + q * 4];
    f32x4 ad = *(const f32x4*)&wd_s[k0 + q * 4];
#pragma unroll
    for (int e = 0; e < 4; ++e) {
      ps0 += h0[e] * as[e]; pd0 += h0[e] * ad[e];
      ps1 += h1[e] * as[e]; pd1 += h1[e] * ad[e];
    }
    u16x4 u0, u1;
#pragma unroll
    for (int e = 0; e < 4; ++e) { u0[e] = bf16_bits(h0[e]); u1[e] = bf16_bits(h1[e]); }
    const int g8 = q >> 1, hh = (q & 1) * 4;
    *(u16x4*)&h_s[lrow * 64 + ((g8 ^ (lrow & 7)) * 8) + hh] = u0;
    const int r1 = lrow + 16;
    *(u16x4*)&h_s[r1 * 64 + ((g8 ^ (r1 & 7)) * 8) + hh] = u1;
    __syncthreads();

#pragma unroll
    for (int mt = 0; mt < 2; ++mt) {
      const int arow = mt * 16 + l15;
#pragma unroll
      for (int s = 0; s < 2; ++s) {
        bf16x8 af = *(const bf16x8*)&h_s[arow * 64 + (((s * 4 + g) ^ (arow & 7)) * 8)];
#pragma unroll
        for (int ntl = 0; ntl < 2; ++ntl) {
          const int nt = wave * 2 + ntl;
          bf16x8 bfv = *(const bf16x8*)&WT[(size_t)(nt * 16 + l15) * F_IN + k0 + s * 32 + g * 8];
          acc[mt][ntl] = __builtin_amdgcn_mfma_f32_16x16x32_bf16(af, bfv, acc[mt][ntl], 0, 0, 0);
        }
      }
    }
    __syncthreads();
  }

  // exact fp32 src/dst: reduce over the 16 lanes sharing a row
#pragma unroll
  for (int m = 1; m <= 8; m <<= 1) {
    ps0 += __shfl_xor(ps0, m); ps1 += __shfl_xor(ps1, m);
    pd0 += __shfl_xor(pd0, m); pd1 += __shfl_xor(pd1, m);
  }
  if (q == 0) {
    srcv[row0 + lrow] = ps0; srcv[row0 + 16 + lrow] = ps1;
    dstv[row0 + lrow] = pd0; dstv[row0 + 16 + lrow] = pd1;
  }

  // split hi/lo transpose via LDS.
  // D layout (measured): col = lane&15 (+16*nt), row = (lane>>4)*4 + reg.
#pragma unroll
  for (int mt = 0; mt < 2; ++mt)
#pragma unroll
    for (int ntl = 0; ntl < 2; ++ntl) {
      const int col = (wave * 2 + ntl) * 16 + l15;
#pragma unroll
      for (int r = 0; r < 4; ++r) {
        const int orow = mt * 16 + g * 4 + r;
        float v = acc[mt][ntl][r];
        bf16_t hb = (bf16_t)v;
        bf16_t lb = (bf16_t)(v - (float)hb);
        t_s[col * 40 + orow] =
            (unsigned)__builtin_bit_cast(unsigned short, hb) |
            ((unsigned)__builtin_bit_cast(unsigned short, lb) << 16);
      }
    }
  __syncthreads();
  const int scol = tid >> 1, hf = tid & 1;
  u16x8 hi0, hi1, lo0, lo1;
#pragma unroll
  for (int i = 0; i < 8; ++i) {
    unsigned v0 = t_s[scol * 40 + hf * 16 + i];
    unsigned v1 = t_s[scol * 40 + hf * 16 + 8 + i];
    hi0[i] = (unsigned short)(v0 & 0xffff); lo0[i] = (unsigned short)(v0 >> 16);
    hi1[i] = (unsigned short)(v1 & 0xffff); lo1[i] = (unsigned short)(v1 >> 16);
  }
  *(u16x8*)(HpTh + (size_t)scol * N_NODES + row0 + hf * 16)     = hi0;
  *(u16x8*)(HpTh + (size_t)scol * N_NODES + row0 + hf * 16 + 8) = hi1;
  *(u16x8*)(HpTl + (size_t)scol * N_NODES + row0 + hf * 16)     = lo0;
  *(u16x8*)(HpTl + (size_t)scol * N_NODES + row0 + hf * 16 + 8) = lo1;
}

// ---------------------------------------------------------------------------
// attn_kernel: out[i] = (sum_j w_ij * Hp[j]) / (sum_j w_ij)
//   w_ij = adj[i][j] != 0 ? exp(leaky_relu(src_i + dst_j)) : 1   (exp(0)=1)
// BM=32 rows/block, grid 256 x 512 threads (8 waves = 2 row-groups x 4
// j-stripes). Zero barriers in the main loop: each wave owns disjoint
// j-stripes; adj loaded directly in MFMA A-fragment layout. Z accumulated
// from the SAME bf16-rounded w used in the numerator (dominant-term
// quantization cancels). Numerator: split hi/lo bf16 MFMA (2 per fragment).
// ---------------------------------------------------------------------------
__global__ __launch_bounds__(512, 2) void attn_kernel(
    const float* __restrict__ adj, const bf16_t* __restrict__ HpTh,
    const bf16_t* __restrict__ HpTl,
    const float* __restrict__ srcv, const float* __restrict__ dstv,
    float* __restrict__ out)
{
  __shared__ float smem[N_NODES];   // dst staging; later numerator partials
  __shared__ float zred[8][16];

  const int tid  = threadIdx.x;
  const int wave = tid >> 6;
  const int lane = tid & 63;
  const int l15  = lane & 15;
  const int g    = lane >> 4;
  const int rg   = wave & 1;   // row-group 0/1
  const int ws   = wave >> 1;  // j-stripe 0..3
  const int row0 = blockIdx.x * 32;
  const int myrow = row0 + rg * 16 + l15;

  for (int i = tid; i < N_NODES / 4; i += 512)
    *(f32x4*)&smem[i * 4] = *(const f32x4*)&dstv[i * 4];
  const float my_src = srcv[myrow];
  __syncthreads();

  f32x4 zero4 = {0.f, 0.f, 0.f, 0.f};
  f32x4 acc[8];
#pragma unroll
  for (int nt = 0; nt < 8; ++nt) acc[nt] = zero4;
  float z_acc = 0.f;

  const float* adj_row = adj + (size_t)myrow * N_NODES;
  const int jg = g * 8;

  // prefetch t=0 (register double buffer; no barriers -> stays in flight)
  f32x4 aA = *(const f32x4*)&adj_row[ws * 32 + jg];
  f32x4 aB = *(const f32x4*)&adj_row[ws * 32 + jg + 4];

  for (int t = 0; t < 64; ++t) {
    const int jc = (t * 4 + ws) * 32 + jg;
    const int tn = (t < 63) ? t + 1 : 63;          // branchless clamped prefetch
    const int jn = (tn * 4 + ws) * 32 + jg;
    f32x4 nA = *(const f32x4*)&adj_row[jn];
    f32x4 nB = *(const f32x4*)&adj_row[jn + 4];

    f32x4 d0 = *(const f32x4*)&smem[jc];
    f32x4 d1 = *(const f32x4*)&smem[jc + 4];

    bf16x8 afr;
#pragma unroll
    for (int e = 0; e < 4; ++e) {
      float s  = my_src + d0[e];
      float lr = s > 0.f ? s : 0.2f * s;
      float wv = (aA[e] != 0.f) ? __expf(lr) : 1.0f;
      bf16_t wq = (bf16_t)wv;
      z_acc += (float)wq;                  // Z from the SAME rounded w
      afr[e] = wq;
    }
#pragma unroll
    for (int e = 0; e < 4; ++e) {
      float s  = my_src + d1[e];
      float lr = s > 0.f ? s : 0.2f * s;
      float wv = (aB[e] != 0.f) ? __expf(lr) : 1.0f;
      bf16_t wq = (bf16_t)wv;
      z_acc += (float)wq;
      afr[4 + e] = wq;
    }

#pragma unroll
    for (int nt = 0; nt < 8; ++nt) {
      bf16x8 bh = *(const bf16x8*)&HpTh[(size_t)(nt * 16 + l15) * N_NODES + jc];
      bf16x8 bl = *(const bf16x8*)&HpTl[(size_t)(nt * 16 + l15) * N_NODES + jc];
      acc[nt] = __builtin_amdgcn_mfma_f32_16x16x32_bf16(afr, bh, acc[nt], 0, 0, 0);
      acc[nt] = __builtin_amdgcn_mfma_f32_16x16x32_bf16(afr, bl, acc[nt], 0, 0, 0);
    }

    aA = nA; aB = nB;
  }

  // Z: sum the 4 g-groups within the wave (rows = lane&15)
  float zc = z_acc + __shfl_xor(z_acc, 16);
  zc += __shfl_xor(zc, 32);
  if (lane < 16) zred[wave][lane] = zc;
  __syncthreads();   // also: all dst reads from smem are done

  // row-group 0: per-stripe partials [ws][16][128], combine, store
  if (rg == 0) {
#pragma unroll
    for (int nt = 0; nt < 8; ++nt)
#pragma unroll
      for (int r = 0; r < 4; ++r)
        smem[ws * 2048 + (g * 4 + r) * 128 + nt * 16 + l15] = acc[nt][r];
  }
  __syncthreads();
  {
    const int orow = tid >> 5;          // 0..15
    const int c0   = (tid & 31) * 4;
    f32x4 s = zero4;
#pragma unroll
    for (int w2 = 0; w2 < 4; ++w2)
      s += *(const f32x4*)&smem[w2 * 2048 + orow * 128 + c0];
    const float zt = zred[0][orow] + zred[2][orow] + zred[4][orow] + zred[6][orow];
    *(f32x4*)&out[(size_t)(row0 + orow) * F_OUT + c0] = s * (1.0f / zt);
  }
  __syncthreads();

  // row-group 1
  if (rg == 1) {
#pragma unroll
    for (int nt = 0; nt < 8; ++nt)
#pragma unroll
      for (int r = 0; r < 4; ++r)
        smem[ws * 2048 + (g * 4 + r) * 128 + nt * 16 + l15] = acc[nt][r];
  }
  __syncthreads();
  {
    const int orow = tid >> 5;
    const int c0   = (tid & 31) * 4;
    f32x4 s = zero4;
#pragma unroll
    for (int w2 = 0; w2 < 4; ++w2)
      s += *(const f32x4*)&smem[w2 * 2048 + orow * 128 + c0];
    const float zt = zred[1][orow] + zred[3][orow] + zred[5][orow] + zred[7][orow];
    *(f32x4*)&out[(size_t)(row0 + 16 + orow) * F_OUT + c0] = s * (1.0f / zt);
  }
}

// ---------------------------------------------------------------------------
// launch
// ---------------------------------------------------------------------------
extern "C" void kernel_launch(void* const* d_in, const int* in_sizes, int n_in,
                              void* d_out, int out_size, void* d_ws, size_t ws_size,
                              hipStream_t stream) {
  const float* H   = (const float*)d_in[0];   // [8192][768]
  const float* adj = (const float*)d_in[1];   // [8192][8192]
  const float* W   = (const float*)d_in[2];   // [768][128]
  const float* a   = (const float*)d_in[3];   // [256]
  float* out = (float*)d_out;                 // [8192][128]

  // workspace layout (~4.5 MB)
  char* ws = (char*)d_ws;
  bf16_t* HpTh = (bf16_t*)(ws);                // 128*8192*2 = 2097152
  bf16_t* HpTl = (bf16_t*)(ws + 2097152);      // 2097152
  bf16_t* WT   = (bf16_t*)(ws + 4194304);      // 128*768*2  = 196608
  float*  wxs  = (float*)(ws + 4390912);       // 768*4
  float*  wxd  = (float*)(ws + 4393984);       // 768*4
  float*  srcv = (float*)(ws + 4397056);       // 8192*4
  float*  dstv = (float*)(ws + 4429824);       // 8192*4

  prep_wt   <<<dim3(96),  dim3(256), 0, stream>>>(W, WT);
  prep_waux <<<dim3(192), dim3(256), 0, stream>>>(W, a, wxs, wxd);
  hp_kernel <<<dim3(256), dim3(256), 0, stream>>>(H, WT, wxs, wxd, HpTh, HpTl, srcv, dstv);
  attn_kernel<<<dim3(256), dim3(512), 0, stream>>>(adj, HpTh, HpTl, srcv, dstv, out);
}

// Round 3
// 410.538 us; speedup vs baseline: 1.4588x; 1.4588x over previous
//
#include <hip/hip_runtime.h>
#include <hip/hip_bf16.h>
#include <stdint.h>

// Problem constants
#define N_NODES 8192
#define F_IN    768
#define F_OUT   128

typedef _Float16 f16_t;
typedef _Float16 f16x8 __attribute__((ext_vector_type(8)));
typedef _Float16 f16x4 __attribute__((ext_vector_type(4)));
typedef float  f32x4  __attribute__((ext_vector_type(4)));
typedef unsigned short u16x4 __attribute__((ext_vector_type(4)));

static __device__ __forceinline__ unsigned short f16_bits(float x) {
  f16_t h = (f16_t)x;   // RTNE
  return __builtin_bit_cast(unsigned short, h);
}

static __device__ __forceinline__ void gload_lds16(const void* g, void* l) {
  __builtin_amdgcn_global_load_lds(
      (const __attribute__((address_space(1))) unsigned int*)g,
      (__attribute__((address_space(3))) unsigned int*)l, 16, 0, 0);
}

// ---------------------------------------------------------------------------
// prep_wt: WT[col][k] = f16(W[k][col])   (128 x 768 f16, L2-resident)
// ---------------------------------------------------------------------------
__global__ __launch_bounds__(256) void prep_wt(const float* __restrict__ W,
                                               f16_t* __restrict__ WT) {
  int gid = blockIdx.x * 256 + threadIdx.x;   // 24576 total
  int col = gid / 192;
  int kq  = gid % 192;
  int k0  = kq * 4;
  u16x4 u;
#pragma unroll
  for (int i = 0; i < 4; ++i)
    u[i] = f16_bits(W[(k0 + i) * F_OUT + col]);
  *(u16x4*)(WT + col * F_IN + k0) = u;
}

// ---------------------------------------------------------------------------
// prep_waux: wxs[k] = sum_c W[k][c]*a[c];  wxd[k] = sum_c W[k][c]*a[128+c]
// ---------------------------------------------------------------------------
__global__ __launch_bounds__(256) void prep_waux(const float* __restrict__ W,
                                                 const float* __restrict__ a,
                                                 float* __restrict__ wxs,
                                                 float* __restrict__ wxd) {
  const int wave = threadIdx.x >> 6;
  const int lane = threadIdx.x & 63;
  const int row  = blockIdx.x * 4 + wave;     // 0..767
  float w0 = W[row * F_OUT + lane];
  float w1 = W[row * F_OUT + 64 + lane];
  float s = w0 * a[lane]       + w1 * a[64 + lane];
  float d = w0 * a[128 + lane] + w1 * a[192 + lane];
#pragma unroll
  for (int m = 1; m <= 32; m <<= 1) {
    s += __shfl_xor(s, m);
    d += __shfl_xor(d, m);
  }
  if (lane == 0) { wxs[row] = s; wxd[row] = d; }
}

// ---------------------------------------------------------------------------
// hp_kernel: Hp = H@W (f16 MFMA), written DIRECTLY in MFMA-B-fragment order:
//   fragment (j32, nt) = 512 f16 at ((j32*8+nt)*512); element (laneB, e)
//   holds Hp[j32*32 + (laneB>>4)*8 + e][nt*16 + (laneB&15)].
// src/dst = H @ wxs/wxd fused into the fp32 H loads (exact fp32).
// BM=32 rows/block (= one j32 per... 32 j = one k-tile of the attn MFMA).
// ---------------------------------------------------------------------------
__global__ __launch_bounds__(256, 2) void hp_kernel(
    const float* __restrict__ H, const f16_t* __restrict__ WT,
    const float* __restrict__ wxs, const float* __restrict__ wxd,
    f16_t* __restrict__ HpP, float* __restrict__ srcv, float* __restrict__ dstv)
{
  __shared__ unsigned short h_s[32 * 64];   // f16 H tile, swizzled
  __shared__ float ws_s[F_IN];
  __shared__ float wd_s[F_IN];

  const int tid  = threadIdx.x;
  const int wave = tid >> 6;
  const int lane = tid & 63;
  const int l15  = lane & 15;
  const int g    = lane >> 4;
  const int row0 = blockIdx.x * 32;
  const int lrow = tid >> 4;   // 0..15
  const int q    = tid & 15;

  for (int i = tid; i < F_IN; i += 256) { ws_s[i] = wxs[i]; wd_s[i] = wxd[i]; }

  f32x4 zero4 = {0.f, 0.f, 0.f, 0.f};
  f32x4 acc[2][2];
#pragma unroll
  for (int i = 0; i < 2; ++i)
#pragma unroll
    for (int j = 0; j < 2; ++j) acc[i][j] = zero4;
  float ps0 = 0.f, ps1 = 0.f, pd0 = 0.f, pd1 = 0.f;

  __syncthreads();

  for (int c = 0; c < F_IN / 64; ++c) {
    const int k0 = c * 64;
    f32x4 h0 = *(const f32x4*)&H[(size_t)(row0 + lrow) * F_IN + k0 + q * 4];
    f32x4 h1 = *(const f32x4*)&H[(size_t)(row0 + 16 + lrow) * F_IN + k0 + q * 4];
    f32x4 as = *(const f32x4*)&ws_s[k0 + q * 4];
    f32x4 ad = *(const f32x4*)&wd_s[k0 + q * 4];
#pragma unroll
    for (int e = 0; e < 4; ++e) {
      ps0 += h0[e] * as[e]; pd0 += h0[e] * ad[e];
      ps1 += h1[e] * as[e]; pd1 += h1[e] * ad[e];
    }
    u16x4 u0, u1;
#pragma unroll
    for (int e = 0; e < 4; ++e) { u0[e] = f16_bits(h0[e]); u1[e] = f16_bits(h1[e]); }
    const int g8 = q >> 1, hh = (q & 1) * 4;
    *(u16x4*)&h_s[lrow * 64 + ((g8 ^ (lrow & 7)) * 8) + hh] = u0;
    const int r1 = lrow + 16;
    *(u16x4*)&h_s[r1 * 64 + ((g8 ^ (r1 & 7)) * 8) + hh] = u1;
    __syncthreads();

#pragma unroll
    for (int mt = 0; mt < 2; ++mt) {
      const int arow = mt * 16 + l15;
#pragma unroll
      for (int s = 0; s < 2; ++s) {
        f16x8 af = *(const f16x8*)&h_s[arow * 64 + (((s * 4 + g) ^ (arow & 7)) * 8)];
#pragma unroll
        for (int ntl = 0; ntl < 2; ++ntl) {
          const int nt = wave * 2 + ntl;
          f16x8 bfv = *(const f16x8*)&WT[(size_t)(nt * 16 + l15) * F_IN + k0 + s * 32 + g * 8];
          acc[mt][ntl] = __builtin_amdgcn_mfma_f32_16x16x32_f16(af, bfv, acc[mt][ntl], 0, 0, 0);
        }
      }
    }
    __syncthreads();
  }

  // exact fp32 src/dst: reduce over the 16 lanes sharing a row
#pragma unroll
  for (int m = 1; m <= 8; m <<= 1) {
    ps0 += __shfl_xor(ps0, m); ps1 += __shfl_xor(ps1, m);
    pd0 += __shfl_xor(pd0, m); pd1 += __shfl_xor(pd1, m);
  }
  if (q == 0) {
    srcv[row0 + lrow] = ps0; srcv[row0 + 16 + lrow] = ps1;
    dstv[row0 + lrow] = pd0; dstv[row0 + 16 + lrow] = pd1;
  }

  // Direct fragment-order store (fully coalesced: each (mt,ntl) store = 512B/wave).
  // D layout: acc[mt][ntl][r] = Hp[row0 + mt*16 + g*4 + r][(wave*2+ntl)*16 + l15]
  const int j32 = row0 >> 5;
#pragma unroll
  for (int mt = 0; mt < 2; ++mt)
#pragma unroll
    for (int ntl = 0; ntl < 2; ++ntl) {
      const int ntB = wave * 2 + ntl;
      const int gB  = mt * 2 + (g >> 1);
      f16x4 v;
#pragma unroll
      for (int r = 0; r < 4; ++r) v[r] = (f16_t)acc[mt][ntl][r];
      const size_t elem = ((size_t)(j32 * 8 + ntB)) * 512 + (gB * 16 + l15) * 8 + (g & 1) * 4;
      *(f16x4*)(HpP + elem) = v;
    }
}

// ---------------------------------------------------------------------------
// attn_kernel: out[i] = (sum_j w_ij * Hp[j]) / (sum_j w_ij)
//   w_ij = exp(lrelu(masked s_ij) - M_i), M_i = max(0, src_i + max_j dst_j)
//   (softmax is shift-invariant -> exact; keeps w <= ~1 so f16 is safe)
// BM=16 rows/block, grid 512 x 512 thr (8 waves = 8 j-stripes of 32).
// adj staged tile-wise [16][256] via global_load_lds with pre-swizzled
// source (16B-unit XOR by row&7); Hp loaded as packed fragments (1KB
// contiguous per load). One barrier per iteration, double-buffered.
// ---------------------------------------------------------------------------
__global__ __launch_bounds__(512, 4) void attn_kernel(
    const float* __restrict__ adj, const f16_t* __restrict__ HpP,
    const float* __restrict__ srcv, const float* __restrict__ dstv,
    float* __restrict__ out)
{
  __shared__ __align__(16) float dst_s[N_NODES];      // 32KB
  __shared__ __align__(16) float adj_s[2][4096];      // 2 x 16KB
  __shared__ float zred[8][16];
  __shared__ float mred[8];

  const int tid  = threadIdx.x;
  const int wave = tid >> 6;
  const int lane = tid & 63;
  const int l15  = lane & 15;
  const int g    = lane >> 4;
  const int row0 = blockIdx.x * 16;

#define STAGE(buf, tt)                                                         \
  do {                                                                         \
    _Pragma("unroll")                                                          \
    for (int rr = 0; rr < 2; ++rr) {                                           \
      const int r = wave * 2 + rr;                                             \
      const float* gp = adj + (size_t)(row0 + r) * N_NODES + (tt) * 256 +      \
                        ((lane ^ (r & 7)) << 2);                               \
      gload_lds16(gp, &adj_s[buf][r * 256]);                                   \
    }                                                                          \
  } while (0)

  // stage tile 0 early (HBM latency hides under dst staging)
  STAGE(0, 0);

  // stage dst + global max(dst)
  float mloc = -3.0e38f;
  for (int i = tid; i < N_NODES / 4; i += 512) {
    f32x4 v = ((const f32x4*)dstv)[i];
    ((f32x4*)dst_s)[i] = v;
    mloc = fmaxf(mloc, fmaxf(fmaxf(v[0], v[1]), fmaxf(v[2], v[3])));
  }
#pragma unroll
  for (int m = 1; m <= 32; m <<= 1) mloc = fmaxf(mloc, __shfl_xor(mloc, m));
  if (lane == 0) mred[wave] = mloc;

  const float my_src = srcv[row0 + l15];
  __syncthreads();

  float maxdst = mred[0];
#pragma unroll
  for (int w2 = 1; w2 < 8; ++w2) maxdst = fmaxf(maxdst, mred[w2]);
  const float Mi    = fmaxf(0.f, my_src + maxdst);
  const float wmask = __expf(-Mi);        // masked entries: exp(0 - Mi)

  // precomputed swizzled LDS read offsets (constant per thread!)
  const int swz  = l15 & 7;
  const int uA   = wave * 8 + g * 2;
  const int offA = l15 * 256 + ((uA ^ swz) << 2);
  const int offB = l15 * 256 + (((uA + 1) ^ swz) << 2);
  const int dstoff = wave * 32 + g * 8;

  f32x4 zero4 = {0.f, 0.f, 0.f, 0.f};
  f32x4 acc[8];
#pragma unroll
  for (int nt = 0; nt < 8; ++nt) acc[nt] = zero4;
  float z_acc = 0.f;

  for (int t = 0; t < 32; ++t) {
    const int cur = t & 1;
    if (t < 31) STAGE(cur ^ 1, t + 1);

    // Hp fragment loads: 8 x 1KB contiguous
    const f16_t* hb = HpP + ((size_t)(t * 8 + wave) * 8) * 512 + lane * 8;
    f16x8 bf[8];
#pragma unroll
    for (int nt = 0; nt < 8; ++nt) bf[nt] = *(const f16x8*)(hb + nt * 512);

    const float* ab = &adj_s[cur][0];
    f32x4 a0 = *(const f32x4*)(ab + offA);
    f32x4 a1 = *(const f32x4*)(ab + offB);
    f32x4 d0 = *(const f32x4*)&dst_s[t * 256 + dstoff];
    f32x4 d1 = *(const f32x4*)&dst_s[t * 256 + dstoff + 4];

    f16x8 afr;
#pragma unroll
    for (int e = 0; e < 4; ++e) {
      float s  = my_src + d0[e];
      float lr = fmaxf(s, 0.2f * s);
      float w  = (a0[e] != 0.f) ? __expf(lr - Mi) : wmask;
      f16_t wq = (f16_t)w;
      z_acc += (float)wq;                 // Z from the SAME rounded w
      afr[e] = wq;
    }
#pragma unroll
    for (int e = 0; e < 4; ++e) {
      float s  = my_src + d1[e];
      float lr = fmaxf(s, 0.2f * s);
      float w  = (a1[e] != 0.f) ? __expf(lr - Mi) : wmask;
      f16_t wq = (f16_t)w;
      z_acc += (float)wq;
      afr[4 + e] = wq;
    }

#pragma unroll
    for (int nt = 0; nt < 8; ++nt)
      acc[nt] = __builtin_amdgcn_mfma_f32_16x16x32_f16(afr, bf[nt], acc[nt], 0, 0, 0);

    __syncthreads();
  }

  // Z: reduce across g-groups (rows = l15)
  float zc = z_acc + __shfl_xor(z_acc, 16);
  zc += __shfl_xor(zc, 32);
  if (lane < 16) zred[wave][lane] = zc;
  __syncthreads();

  // combine 8 stripe-partials in two passes through 32KB LDS (reuse adj_s)
  float* part = &adj_s[0][0];
  if (wave < 4) {
#pragma unroll
    for (int nt = 0; nt < 8; ++nt)
#pragma unroll
      for (int r = 0; r < 4; ++r)
        part[wave * 2048 + (g * 4 + r) * 128 + nt * 16 + l15] = acc[nt][r];
  }
  __syncthreads();
  if (wave >= 4) {
#pragma unroll
    for (int nt = 0; nt < 8; ++nt)
#pragma unroll
      for (int r = 0; r < 4; ++r)
        part[(wave - 4) * 2048 + (g * 4 + r) * 128 + nt * 16 + l15] += acc[nt][r];
  }
  __syncthreads();
  {
    const int orow = tid >> 5;          // 0..15
    const int c0   = (tid & 31) * 4;
    f32x4 s = zero4;
#pragma unroll
    for (int b = 0; b < 4; ++b)
      s += *(const f32x4*)&part[b * 2048 + orow * 128 + c0];
    float zt = 0.f;
#pragma unroll
    for (int w2 = 0; w2 < 8; ++w2) zt += zred[w2][orow];
    *(f32x4*)&out[(size_t)(row0 + orow) * F_OUT + c0] = s * (1.0f / zt);
  }
#undef STAGE
}

// ---------------------------------------------------------------------------
// launch
// ---------------------------------------------------------------------------
extern "C" void kernel_launch(void* const* d_in, const int* in_sizes, int n_in,
                              void* d_out, int out_size, void* d_ws, size_t ws_size,
                              hipStream_t stream) {
  const float* H   = (const float*)d_in[0];   // [8192][768]
  const float* adj = (const float*)d_in[1];   // [8192][8192]
  const float* W   = (const float*)d_in[2];   // [768][128]
  const float* a   = (const float*)d_in[3];   // [256]
  float* out = (float*)d_out;                 // [8192][128]

  // workspace layout (~2.3 MB)
  char* ws = (char*)d_ws;
  f16_t* HpP  = (f16_t*)(ws);                  // 8192*128*2 = 2097152 (fragment-packed)
  f16_t* WT   = (f16_t*)(ws + 2097152);        // 128*768*2  = 196608
  float* wxs  = (float*)(ws + 2293760);        // 768*4
  float* wxd  = (float*)(ws + 2296832);        // 768*4
  float* srcv = (float*)(ws + 2299904);        // 8192*4
  float* dstv = (float*)(ws + 2332672);        // 8192*4

  prep_wt   <<<dim3(96),  dim3(256), 0, stream>>>(W, WT);
  prep_waux <<<dim3(192), dim3(256), 0, stream>>>(W, a, wxs, wxd);
  hp_kernel <<<dim3(256), dim3(256), 0, stream>>>(H, WT, wxs, wxd, HpP, srcv, dstv);
  attn_kernel<<<dim3(512), dim3(512), 0, stream>>>(adj, HpP, srcv, dstv, out);
}